// Round 1
// 241.000 us; speedup vs baseline: 1.0478x; 1.0478x over previous
//
#include <hip/hip_runtime.h>
#include <stdint.h>

#define DEV_INLINE __device__ __forceinline__

typedef __bf16 bf16x8 __attribute__((ext_vector_type(8)));
typedef float f32x4 __attribute__((ext_vector_type(4)));

typedef const __attribute__((address_space(1))) void* gas_ptr;
typedef __attribute__((address_space(3))) void* las_ptr;

DEV_INLINE unsigned short f2bf(float f) {
    union { float f; unsigned u; } v; v.f = f;
    unsigned r = v.u + 0x7fffu + ((v.u >> 16) & 1u);   // RNE
    return (unsigned short)(r >> 16);
}

// Raw workgroup barrier: drains LDS ops (cross-thread visibility) but leaves
// global prefetch loads (vmcnt) in flight across the barrier.
DEV_INLINE void lds_barrier() {
    __builtin_amdgcn_sched_barrier(0);
    asm volatile("s_waitcnt lgkmcnt(0)" ::: "memory");
    __builtin_amdgcn_s_barrier();
    __builtin_amdgcn_sched_barrier(0);
}

// ---------------- prep: casts + bias init (one launch) ----------------
__global__ __launch_bounds__(256)
void prep_cast_kernel(const float* __restrict__ x, unsigned short* __restrict__ xb,
                      const float* __restrict__ Wkv, unsigned short* __restrict__ wkvb,
                      const float* __restrict__ bq, const float* __restrict__ bkv,
                      float* __restrict__ bias1, float* __restrict__ zbuf) {
    int bid = blockIdx.x;
    if (bid < 1536) {
        const float* s; unsigned short* d; long i;
        if (bid < 384) { s = x;   d = xb;   i = (long)bid * 256 + threadIdx.x; }
        else           { s = Wkv; d = wkvb; i = (long)(bid - 384) * 256 + threadIdx.x; }
        float4 a = ((const float4*)s)[i];
        ushort4 o;
        o.x = f2bf(a.x); o.y = f2bf(a.y); o.z = f2bf(a.z); o.w = f2bf(a.w);
        ((ushort4*)d)[i] = o;
    } else {
        int i = (bid - 1536) * 256 + threadIdx.x;   // [0,3072)
        if (i < 768) bias1[i] = bq[i];
        else if (i < 2304) bias1[i] = bkv[i - 768];
        else zbuf[i - 2304] = 0.f;
    }
}

// ---------------- prep: 3 fused transposes (one launch) ----------------
// blockIdx.x: [0,12) Wq -> w1t[0:768], [12,36) Wkv -> w1t[768:2304], [36,48) Wp -> wpt
__global__ void transpose3_kernel(const float* __restrict__ Wq,
                                  const float* __restrict__ Wkv,
                                  const float* __restrict__ Wp,
                                  unsigned short* __restrict__ w1t,
                                  unsigned short* __restrict__ wpt) {
    __shared__ float tl[64][65];
    int bx = blockIdx.x;
    const float* src; unsigned short* dst; int C;
    if (bx < 12)      { src = Wq;  dst = w1t;              C = 768; }
    else if (bx < 36) { src = Wkv; dst = w1t + 768L * 768; C = 1536; bx -= 12; }
    else              { src = Wp;  dst = wpt;              C = 768; bx -= 36; }
    int c0 = bx * 64, r0 = blockIdx.y * 64;
    int tx = threadIdx.x, ty = threadIdx.y;   // 64 x 16
    #pragma unroll
    for (int i = 0; i < 64; i += 16)
        tl[ty + i][tx] = src[(long)(r0 + ty + i) * C + c0 + tx];
    __syncthreads();
    #pragma unroll
    for (int i = 0; i < 64; i += 16)
        dst[(long)(c0 + ty + i) * 768 + r0 + tx] = f2bf(tl[tx][ty + i]);
}

// ---------------- unified bf16 MFMA GEMM body ----------------
// A: rows x K bf16 (lda). BT: cols x K bf16 (ldb) == B^T. Staged via
// global_load_lds w=16 with XOR chunk swizzle. Tile TR x TC.
// Concat-K: for k0 >= K1 switch to A2/lda2, B2/ldb2 (kc = k0-K1).
// OUT (runtime): 0=f32 store, 1=bf16 store. cin != nullptr: fp32 add.
// G1E (template): GEMM1 special epilogue (qf/qb, kxb, vxT-transposed).
template <int WM, int WN, int WAVES_M, bool G1E>
DEV_INLINE void gemm_body(const unsigned short* A, int lda,
                          const unsigned short* BT, int ldb,
                          const unsigned short* A2, int lda2,
                          const unsigned short* B2, int ldb2, int K1,
                          const float* bias, void* Cout, int ldc, int K,
                          const float* cin, int OUT, long obase, long tm, long tn,
                          unsigned short* As, unsigned short* Bs,
                          float* g1_qf, unsigned short* g1_qb,
                          unsigned short* g1_kxb, unsigned short* g1_vxT) {
    constexpr int TR = WAVES_M * WM * 16;
    constexpr int TC = (4 / WAVES_M) * WN * 16;
    const int tid = threadIdx.x;
    const int w = tid >> 6, lane = tid & 63;
    const int lm = lane & 15, quad = lane >> 4;
    const int m_off = (w % WAVES_M) * WM * 16;
    const int n_off = (w / WAVES_M) * WN * 16;
    const int lrow8 = lane >> 3;
    const int lcol_sw = (((lane & 7) ^ lrow8) * 8);

    f32x4 acc[WM][WN];
    #pragma unroll
    for (int mi = 0; mi < WM; ++mi)
        #pragma unroll
        for (int ni = 0; ni < WN; ++ni) acc[mi][ni] = f32x4{0.f, 0.f, 0.f, 0.f};

    for (int k0 = 0; k0 < K; k0 += 64) {
        const unsigned short* Ab; const unsigned short* Bb;
        int la, lb, kc;
        if (k0 < K1) { Ab = A;  Bb = BT; la = lda;  lb = ldb;  kc = k0; }
        else         { Ab = A2; Bb = B2; la = lda2; lb = ldb2; kc = k0 - K1; }
        __syncthreads();
        #pragma unroll
        for (int i = 0; i < TR / 32; ++i) {
            int rr = w * (TR / 4) + i * 8;
            const unsigned short* ga = Ab + (tm + rr + lrow8) * la + kc + lcol_sw;
            __builtin_amdgcn_global_load_lds((gas_ptr)ga, (las_ptr)(As + rr * 64), 16, 0, 0);
        }
        #pragma unroll
        for (int i = 0; i < TC / 32; ++i) {
            int rr = w * (TC / 4) + i * 8;
            const unsigned short* gb = Bb + (tn + rr + lrow8) * lb + kc + lcol_sw;
            __builtin_amdgcn_global_load_lds((gas_ptr)gb, (las_ptr)(Bs + rr * 64), 16, 0, 0);
        }
        __syncthreads();
        #pragma unroll
        for (int kk = 0; kk < 2; ++kk) {
            bf16x8 af[WM], bfr[WN];
            #pragma unroll
            for (int mi = 0; mi < WM; ++mi) {
                int r = m_off + mi * 16 + lm;
                af[mi] = *(const bf16x8*)(As + r * 64 + (((kk * 4 + quad) ^ (r & 7)) * 8));
            }
            #pragma unroll
            for (int ni = 0; ni < WN; ++ni) {
                int r = n_off + ni * 16 + lm;
                bfr[ni] = *(const bf16x8*)(Bs + r * 64 + (((kk * 4 + quad) ^ (r & 7)) * 8));
            }
            #pragma unroll
            for (int mi = 0; mi < WM; ++mi)
                #pragma unroll
                for (int ni = 0; ni < WN; ++ni)
                    acc[mi][ni] = __builtin_amdgcn_mfma_f32_16x16x32_bf16(
                        af[mi], bfr[ni], acc[mi][ni], 0, 0, 0);
        }
    }

    #pragma unroll
    for (int mi = 0; mi < WM; ++mi) {
        #pragma unroll
        for (int ni = 0; ni < WN; ++ni) {
            long col = tn + n_off + ni * 16 + lm;
            float bv = bias[col];
            #pragma unroll
            for (int r = 0; r < 4; ++r) {
                long row = tm + m_off + mi * 16 + quad * 4 + r;   // C/D: col=lane&15, row=quad*4+reg
                float v = acc[mi][ni][r] + bv;
                if (G1E) {
                    if (col < 768) {
                        g1_qf[row * 768 + col] = v;
                        g1_qb[row * 768 + col] = f2bf(v);
                    } else if (col < 1536) {
                        g1_kxb[row * 768 + (col - 768)] = f2bf(v);
                    } else {
                        int j = (int)col - 1536, h = j >> 6, d = j & 63;
                        int bb = (int)row >> 8, nn = (int)row & 255;
                        g1_vxT[((long)(bb * 12 + h) * 64 + d) * 256 + nn] = f2bf(v);
                    }
                } else {
                    long idx = obase + row * ldc + col;
                    if (cin) v += cin[idx];
                    if (OUT == 0) ((float*)Cout)[idx] = v;
                    else ((unsigned short*)Cout)[idx] = f2bf(v);
                }
            }
        }
    }
}

// standard wrapper: batch z -> zb=z/12, zh=z%12
template <int WM, int WN, int WAVES_M, bool G1E>
__global__ __launch_bounds__(256)
void gemm_bf16_kernel(const unsigned short* __restrict__ A, int lda,
                      const unsigned short* __restrict__ BT, int ldb,
                      const float* __restrict__ bias,
                      void* __restrict__ Cout, int ldc, int K,
                      const float* __restrict__ cin, int OUT,
                      long aZb, long aZh, long bZb, long bZh, long oZb, long oZh,
                      float* __restrict__ g1_qf, unsigned short* __restrict__ g1_qb,
                      unsigned short* __restrict__ g1_kxb,
                      unsigned short* __restrict__ g1_vxT) {
    constexpr int TR = WAVES_M * WM * 16;
    constexpr int TC = (4 / WAVES_M) * WN * 16;
    __shared__ unsigned short As[TR * 64];
    __shared__ unsigned short Bs[TC * 64];
    const int z = blockIdx.z, zb = z / 12, zh = z % 12;
    gemm_body<WM, WN, WAVES_M, G1E>(
        A + zb * aZb + zh * aZh, lda, BT + zb * bZb + zh * bZh, ldb,
        nullptr, 0, nullptr, 0, 1 << 30,
        bias, Cout, ldc, K, cin, OUT, zb * oZb + zh * oZh,
        (long)blockIdx.y * TR, (long)blockIdx.x * TC, As, Bs,
        g1_qf, g1_qb, g1_kxb, g1_vxT);
}

// fused qW + SG launch (both depend only on GEMM1): 1D grid of 1152 + 384
__global__ __launch_bounds__(256)
void gemm_qwsg_kernel(const unsigned short* __restrict__ qb,
                      const unsigned short* __restrict__ wkvb,
                      const unsigned short* __restrict__ kxb,
                      const float* __restrict__ zbuf,
                      unsigned short* __restrict__ qWb,
                      float* __restrict__ sgbuf) {
    __shared__ unsigned short As[64 * 64];
    __shared__ unsigned short Bs[64 * 64];
    int bid = blockIdx.x;
    if (bid < 1152) {
        // qW: qW_h = q_h @ Wk_h^T  (512x768, K=64), bf16 out
        int bx = bid % 12, by = (bid / 12) % 8, h = bid / 96;
        gemm_body<2, 2, 2, false>(
            qb + h * 64, 768, wkvb + h * 64, 1536,
            nullptr, 0, nullptr, 0, 1 << 30,
            zbuf, qWb, 768, 64, nullptr, 1, (long)h * 393216,
            (long)by * 64, (long)bx * 64, As, Bs,
            nullptr, nullptr, nullptr, nullptr);
    } else {
        // SG: sg = q_h @ k_x,h^T per (b,h)  (256x256, K=64), fp32 out
        int bid2 = bid - 1152;
        int bx = bid2 % 4, by = (bid2 / 4) % 4, z = bid2 / 16;
        int zb = z / 12, zh = z % 12;
        gemm_body<2, 2, 2, false>(
            qb + zb * 196608 + zh * 64, 768, kxb + zb * 196608 + zh * 64, 768,
            nullptr, 0, nullptr, 0, 1 << 30,
            zbuf, sgbuf, 256, 64, nullptr, 0,
            (long)zb * 786432 + (long)zh * 65536,
            (long)by * 64, (long)bx * 64, As, Bs,
            nullptr, nullptr, nullptr, nullptr);
    }
}

// concat-K wrapper: attnb = bf16([simbar | ag] @ [WvT | vxT]^T + outg0)
template <int WM, int WN, int WAVES_M>
__global__ __launch_bounds__(256)
void gemm_concat_kernel(const unsigned short* __restrict__ A, int lda, long aZb, long aZh,
                        const unsigned short* __restrict__ BT, int ldb, long bZb, long bZh,
                        const unsigned short* __restrict__ A2, int lda2, long a2Zb, long a2Zh,
                        const unsigned short* __restrict__ B2, int ldb2, long b2Zb, long b2Zh,
                        int K1, int K, const float* __restrict__ bias,
                        void* __restrict__ Cout, int ldc,
                        const float* __restrict__ cin, int OUT, long oZb, long oZh) {
    constexpr int TR = WAVES_M * WM * 16;
    constexpr int TC = (4 / WAVES_M) * WN * 16;
    __shared__ unsigned short As[TR * 64];
    __shared__ unsigned short Bs[TC * 64];
    const int z = blockIdx.z, zb = z / 12, zh = z % 12;
    gemm_body<WM, WN, WAVES_M, false>(
        A + zb * aZb + zh * aZh, lda, BT + zb * bZb + zh * bZh, ldb,
        A2 + zb * a2Zb + zh * a2Zh, lda2, B2 + zb * b2Zb + zh * b2Zh, ldb2, K1,
        bias, Cout, ldc, K, cin, OUT, zb * oZb + zh * oZh,
        (long)blockIdx.y * TR, (long)blockIdx.x * TC, As, Bs,
        nullptr, nullptr, nullptr, nullptr);
}

// ---------------- fused attention: sl MFMA + softmax (pipelined) ----------------
// Block per n_ = b*256+n, 256 threads (4 waves).
// Pass 1 pipelined: register double-prefetch of the next 64-wide sim chunk,
// double-buffered LDS, raw lds_barrier (lgkmcnt-only) so prefetch loads stay
// in flight across the barrier (no vmcnt(0) drain per chunk).
// Softmax over [sg(256)|sl(64)] per head; ag -> agb bf16; al -> al_g fp32
// (consumed by simbar_kernel); alm*bkv_v -> outg0.
__global__ __launch_bounds__(256)
void attn_fused_kernel(const float* __restrict__ sim,
                       const unsigned short* __restrict__ qWb,
                       const float* __restrict__ qf,
                       const float* __restrict__ bkv,
                       const float* __restrict__ sgbuf,
                       unsigned short* __restrict__ agb,
                       float* __restrict__ outg0,
                       float* __restrict__ al_g) {
    __shared__ unsigned short qw_s[16 * 784];     // heads 12-15 junk rows
    __shared__ unsigned short sim_s[2][64 * 64];  // double-buffered, XOR-swizzled
    __shared__ float q_l[768];
    __shared__ float slb_s[12];
    __shared__ float scl[12][68];

    const int t = threadIdx.x;
    const int lane = t & 63, w = t >> 6;
    const int lm = lane & 15, quad = lane >> 4;
    const int n = blockIdx.x, b = blockIdx.y;
    const int n_ = b * 256 + n;
    const float* simn = sim + (long)n_ * 49152;   // 64 x 768

    // stage qW rows (h = t>>4, 6 chunks each) and q
    {
        const int h = t >> 4, c0 = t & 15;
        const unsigned short* src = qWb + ((long)h * 512 + n_) * 768;
        #pragma unroll
        for (int j = 0; j < 6; ++j) {
            int ch = c0 + 16 * j;
            *(bf16x8*)(qw_s + h * 784 + ch * 8) = *(const bf16x8*)(src + ch * 8);
        }
    }
    q_l[t] = qf[(long)n_ * 768 + t];
    q_l[t + 256] = qf[(long)n_ * 768 + t + 256];
    q_l[t + 512] = qf[(long)n_ * 768 + t + 512];

    // prefetch chunk 0: thread covers rows r0 (k-cols q8*8..q8*8+8) and r0+32
    const int r0 = t >> 3, q8 = t & 7, r1 = r0 + 32;
    float4 p0a, p0b, p1a, p1b;
    {
        const float* g0 = simn + r0 * 768 + q8 * 8;
        p0a = *(const float4*)g0; p0b = *(const float4*)(g0 + 4);
        const float* g1 = simn + r1 * 768 + q8 * 8;
        p1a = *(const float4*)g1; p1b = *(const float4*)(g1 + 4);
    }
    __syncthreads();   // qw_s, q_l staged
    if (t < 12) {      // sl bias term: q[h] . bkv_k[h]
        float s = 0.f;
        #pragma unroll 8
        for (int d = 0; d < 64; ++d) s += q_l[t * 64 + d] * bkv[t * 64 + d];
        slb_s[t] = s;
    }

    // Pass 1: sl MFMA, pipelined over 12 chunks
    f32x4 acc = {};
    #pragma unroll
    for (int c = 0; c < 12; ++c) {
        const int k0 = c * 64;
        unsigned short* buf = sim_s[c & 1];
        union { bf16x8 v; unsigned short u[8]; } pk;
        pk.u[0] = f2bf(p0a.x); pk.u[1] = f2bf(p0a.y);
        pk.u[2] = f2bf(p0a.z); pk.u[3] = f2bf(p0a.w);
        pk.u[4] = f2bf(p0b.x); pk.u[5] = f2bf(p0b.y);
        pk.u[6] = f2bf(p0b.z); pk.u[7] = f2bf(p0b.w);
        *(bf16x8*)(buf + r0 * 64 + ((q8 ^ (r0 & 7)) * 8)) = pk.v;
        pk.u[0] = f2bf(p1a.x); pk.u[1] = f2bf(p1a.y);
        pk.u[2] = f2bf(p1a.z); pk.u[3] = f2bf(p1a.w);
        pk.u[4] = f2bf(p1b.x); pk.u[5] = f2bf(p1b.y);
        pk.u[6] = f2bf(p1b.z); pk.u[7] = f2bf(p1b.w);
        *(bf16x8*)(buf + r1 * 64 + ((q8 ^ (r1 & 7)) * 8)) = pk.v;
        if (c < 11) {   // prefetch next chunk; stays in flight across lds_barrier
            const float* g0 = simn + r0 * 768 + k0 + 64 + q8 * 8;
            p0a = *(const float4*)g0; p0b = *(const float4*)(g0 + 4);
            const float* g1 = simn + r1 * 768 + k0 + 64 + q8 * 8;
            p1a = *(const float4*)g1; p1b = *(const float4*)(g1 + 4);
        }
        lds_barrier();
        #pragma unroll
        for (int kk = 0; kk < 2; ++kk) {
            int r = w * 16 + lm;
            bf16x8 af = *(const bf16x8*)(buf + r * 64 + (((kk * 4 + quad) ^ (r & 7)) * 8));
            bf16x8 bfr = *(const bf16x8*)(qw_s + lm * 784 + k0 + kk * 32 + quad * 8);
            acc = __builtin_amdgcn_mfma_f32_16x16x32_bf16(af, bfr, acc, 0, 0, 0);
        }
    }
    if (lm < 12) {
        #pragma unroll
        for (int r = 0; r < 4; ++r)
            scl[lm][w * 16 + quad * 4 + r] = (acc[r] + slb_s[lm]) * 0.125f;
    }
    __syncthreads();

    // softmax: wave w handles heads h = 3w..3w+2; 5 scores per lane
    #pragma unroll
    for (int i = 0; i < 3; ++i) {
        const int h = w * 3 + i;
        const float* sgr = sgbuf + (long)(b * 12 + h) * 65536 + (long)n * 256;
        float v0 = sgr[lane] * 0.125f, v1 = sgr[lane + 64] * 0.125f,
              v2 = sgr[lane + 128] * 0.125f, v3 = sgr[lane + 192] * 0.125f;
        float v4 = scl[h][lane];
        float mx = fmaxf(fmaxf(fmaxf(v0, v1), fmaxf(v2, v3)), v4);
        #pragma unroll
        for (int off = 32; off > 0; off >>= 1) mx = fmaxf(mx, __shfl_xor(mx, off));
        float e0 = __expf(v0 - mx), e1 = __expf(v1 - mx), e2 = __expf(v2 - mx),
              e3 = __expf(v3 - mx), e4 = __expf(v4 - mx);
        float s = e0 + e1 + e2 + e3 + e4;
        #pragma unroll
        for (int off = 32; off > 0; off >>= 1) s += __shfl_xor(s, off);
        float inv = __frcp_rn(s);
        unsigned short* agr = agb + (long)(b * 12 + h) * 65536 + (long)n * 256;
        agr[lane] = f2bf(e0 * inv); agr[lane + 64] = f2bf(e1 * inv);
        agr[lane + 128] = f2bf(e2 * inv); agr[lane + 192] = f2bf(e3 * inv);
        float al = e4 * inv;
        al_g[(long)n_ * 768 + h * 64 + lane] = al;
        float am = al;
        #pragma unroll
        for (int off = 32; off > 0; off >>= 1) am += __shfl_xor(am, off);
        outg0[(long)n_ * 768 + h * 64 + lane] = am * bkv[768 + h * 64 + lane];
    }
}

// ---------------- simbar: wide, high-occupancy (sim re-read is L3-hot) ----------------
// grid (512 n_, 3 col-chunks); simbar[h][n_][c] = sum_m al[h][m] * sim[n_][m][c]
__global__ __launch_bounds__(256)
void simbar_kernel(const float* __restrict__ sim,
                   const float* __restrict__ al_g,
                   unsigned short* __restrict__ simbar) {
    __shared__ float al_l[768];
    const int t = threadIdx.x;
    const int n_ = blockIdx.x;
    const int c = blockIdx.y * 256 + t;
    const float* simn = sim + (long)n_ * 49152;
    al_l[t] = al_g[(long)n_ * 768 + t];
    al_l[t + 256] = al_g[(long)n_ * 768 + t + 256];
    al_l[t + 512] = al_g[(long)n_ * 768 + t + 512];
    __syncthreads();
    float a[12];
    #pragma unroll
    for (int h = 0; h < 12; ++h) a[h] = 0.f;
    #pragma unroll 4
    for (int m = 0; m < 64; ++m) {
        float s = simn[(long)m * 768 + c];
        #pragma unroll
        for (int h = 0; h < 12; ++h) a[h] += al_l[h * 64 + m] * s;
    }
    #pragma unroll
    for (int h = 0; h < 12; ++h)
        simbar[((long)h * 512 + n_) * 768 + c] = f2bf(a[h]);
}

// ---------------- launch ----------------

extern "C" void kernel_launch(void* const* d_in, const int* in_sizes, int n_in,
                              void* d_out, int out_size, void* d_ws, size_t ws_size,
                              hipStream_t stream) {
    const float* x   = (const float*)d_in[0];   // (2,256,768)
    const float* sim = (const float*)d_in[1];   // (2,256,64,768)
    const float* Wq  = (const float*)d_in[2];   // (768,768)
    const float* bq  = (const float*)d_in[3];   // (768)
    const float* Wkv = (const float*)d_in[4];   // (768,1536)
    const float* bkv = (const float*)d_in[5];   // (1536)
    const float* Wp  = (const float*)d_in[6];   // (768,768)
    const float* bp  = (const float*)d_in[7];   // (768)
    float* out = (float*)d_out;                 // (2,256,768) fp32

    char* ws = (char*)d_ws;
    size_t off = 0;
    auto alloc = [&](size_t bytes) {
        char* p = ws + off;
        off += (bytes + 255) & ~(size_t)255;
        return p;
    };
    unsigned short* xb     = (unsigned short*)alloc(512UL * 768 * 2);       // x bf16
    unsigned short* w1t    = (unsigned short*)alloc(2304UL * 768 * 2);      // [Wq|Wkv]^T bf16
    unsigned short* wkvb   = (unsigned short*)alloc(768UL * 1536 * 2);      // Wkv bf16
    unsigned short* wpt    = (unsigned short*)alloc(768UL * 768 * 2);       // Wp^T bf16
    float*          qf     = (float*)alloc(512UL * 768 * 4);                // q fp32
    unsigned short* qb     = (unsigned short*)alloc(512UL * 768 * 2);       // q bf16
    unsigned short* kxb    = (unsigned short*)alloc(512UL * 768 * 2);       // k_x bf16
    unsigned short* vxT    = (unsigned short*)alloc(24UL * 64 * 256 * 2);   // v_x^T per (b,h)
    unsigned short* qWb    = (unsigned short*)alloc(16UL * 512 * 768 * 2);  // qW bf16
    float*          sgbuf  = (float*)alloc(24UL * 65536 * 4);               // sg fp32
    unsigned short* agb    = (unsigned short*)alloc(24UL * 65536 * 2);      // ag bf16
    float*          outg0  = (float*)alloc(512UL * 768 * 4);                // alm*bkv_v fp32
    float*          al_g   = (float*)alloc(512UL * 768 * 4);                // al fp32 [n_][h][m]
    unsigned short* simbar = (unsigned short*)alloc(12UL * 512 * 768 * 2);  // simbar bf16
    unsigned short* attnb  = (unsigned short*)alloc(512UL * 768 * 2);       // attn out bf16
    float*          bias1  = (float*)alloc(2304UL * 4);                     // [bq|bkv]
    float*          zbuf   = (float*)alloc(768UL * 4);                      // zeros

    // prep (2 launches)
    prep_cast_kernel<<<1548, 256, 0, stream>>>(x, xb, Wkv, wkvb, bq, bkv, bias1, zbuf);
    transpose3_kernel<<<dim3(48, 12), dim3(64, 16), 0, stream>>>(Wq, Wkv, Wp, w1t, wpt);

    // GEMM1: x @ [Wq|Wkv] + bias -> qf/qb, kxb, vxT   (512 x 2304, K=768)
    gemm_bf16_kernel<2, 2, 2, true><<<dim3(36, 8, 1), 256, 0, stream>>>(
        xb, 768, w1t, 768, bias1, nullptr, 768, 768, nullptr, 0,
        0, 0, 0, 0, 0, 0, qf, qb, kxb, vxT);

    // qW (512x768 K=64 per head) + SG (256x256 K=64 per (b,h)) fused: 1536 blocks
    gemm_qwsg_kernel<<<1536, 256, 0, stream>>>(qb, wkvb, kxb, zbuf, qWb, sgbuf);

    // fused attention: pipelined sl MFMA + softmax
    attn_fused_kernel<<<dim3(256, 2), 256, 0, stream>>>(
        sim, qWb, qf, bkv, sgbuf, agb, outg0, al_g);

    // simbar: al @ sim, wide grid (sim L3-hot)
    simbar_kernel<<<dim3(512, 3), 256, 0, stream>>>(sim, al_g, simbar);

    // attnb = bf16([simbar | ag] @ [WvT | vxT]^T + outg0), per (b,h), K=768+256
    gemm_concat_kernel<1, 1, 2><<<dim3(2, 8, 24), 256, 0, stream>>>(
        simbar, 768, 196608, 393216,
        w1t + 1536L * 768, 768, 0, 49152,
        agb, 256, 786432, 65536,
        vxT, 256, 196608, 16384,
        768, 1024, zbuf, attnb, 768, outg0, 1, 196608, 64);

    // GEMM3: out = attnb @ Wp + bp   (512x768, K=768), 32x32 tiles -> 384 blocks
    gemm_bf16_kernel<1, 1, 2, false><<<dim3(24, 16, 1), 256, 0, stream>>>(
        attnb, 768, wpt, 768, bp, out, 768, 768, nullptr, 0,
        0, 0, 0, 0, 0, 0, nullptr, nullptr, nullptr, nullptr);
}

// Round 2
// 236.061 us; speedup vs baseline: 1.0697x; 1.0209x over previous
//
#include <hip/hip_runtime.h>
#include <stdint.h>

#define DEV_INLINE __device__ __forceinline__

typedef __bf16 bf16x8 __attribute__((ext_vector_type(8)));
typedef float f32x4 __attribute__((ext_vector_type(4)));

typedef const __attribute__((address_space(1))) void* gas_ptr;
typedef __attribute__((address_space(3))) void* las_ptr;

DEV_INLINE unsigned short f2bf(float f) {
    union { __bf16 h; unsigned short u; } v;
    v.h = (__bf16)f;            // native RNE cvt (v_cvt_pk_bf16_f32 on gfx950)
    return v.u;
}

template <int N> DEV_INLINE void waitcnt_vm() {
    asm volatile("s_waitcnt vmcnt(%0)" :: "n"(N) : "memory");
}
DEV_INLINE void hard_barrier() {
    __builtin_amdgcn_sched_barrier(0);
    __builtin_amdgcn_s_barrier();
    __builtin_amdgcn_sched_barrier(0);
}
// LDS-visibility barrier (drains ds ops, leaves global loads in flight)
DEV_INLINE void lds_barrier() {
    __builtin_amdgcn_sched_barrier(0);
    asm volatile("s_waitcnt lgkmcnt(0)" ::: "memory");
    __builtin_amdgcn_s_barrier();
    __builtin_amdgcn_sched_barrier(0);
}

// ---------------- prep: casts + bias init (one launch) ----------------
__global__ __launch_bounds__(256)
void prep_cast_kernel(const float* __restrict__ x, unsigned short* __restrict__ xb,
                      const float* __restrict__ Wkv, unsigned short* __restrict__ wkvb,
                      const float* __restrict__ bq, const float* __restrict__ bkv,
                      float* __restrict__ bias1, float* __restrict__ zbuf) {
    int bid = blockIdx.x;
    if (bid < 1536) {
        const float* s; unsigned short* d; long i;
        if (bid < 384) { s = x;   d = xb;   i = (long)bid * 256 + threadIdx.x; }
        else           { s = Wkv; d = wkvb; i = (long)(bid - 384) * 256 + threadIdx.x; }
        float4 a = ((const float4*)s)[i];
        ushort4 o;
        o.x = f2bf(a.x); o.y = f2bf(a.y); o.z = f2bf(a.z); o.w = f2bf(a.w);
        ((ushort4*)d)[i] = o;
    } else {
        int i = (bid - 1536) * 256 + threadIdx.x;   // [0,3072)
        if (i < 768) bias1[i] = bq[i];
        else if (i < 2304) bias1[i] = bkv[i - 768];
        else zbuf[i - 2304] = 0.f;
    }
}

// ---------------- prep: 3 fused transposes (one launch) ----------------
__global__ void transpose3_kernel(const float* __restrict__ Wq,
                                  const float* __restrict__ Wkv,
                                  const float* __restrict__ Wp,
                                  unsigned short* __restrict__ w1t,
                                  unsigned short* __restrict__ wpt) {
    __shared__ float tl[64][65];
    int bx = blockIdx.x;
    const float* src; unsigned short* dst; int C;
    if (bx < 12)      { src = Wq;  dst = w1t;              C = 768; }
    else if (bx < 36) { src = Wkv; dst = w1t + 768L * 768; C = 1536; bx -= 12; }
    else              { src = Wp;  dst = wpt;              C = 768; bx -= 36; }
    int c0 = bx * 64, r0 = blockIdx.y * 64;
    int tx = threadIdx.x, ty = threadIdx.y;   // 64 x 16
    #pragma unroll
    for (int i = 0; i < 64; i += 16)
        tl[ty + i][tx] = src[(long)(r0 + ty + i) * C + c0 + tx];
    __syncthreads();
    #pragma unroll
    for (int i = 0; i < 64; i += 16)
        dst[(long)(c0 + ty + i) * 768 + r0 + tx] = f2bf(tl[tx][ty + i]);
}

// ---------------- unified bf16 MFMA GEMM body (2-phase pipelined) ----------------
// A: rows x K bf16 (lda). BT: cols x K bf16 (ldb) == B^T. Double-buffered LDS,
// stage(t+1) issued before compute(t), counted vmcnt (never 0 in steady state).
// Concat-K: for k0 >= K1 switch to A2/lda2, B2/ldb2. As/Bs sized 2*TR*64 / 2*TC*64.
template <int WM, int WN, int WAVES_M, bool G1E>
DEV_INLINE void gemm_body(const unsigned short* A, int lda,
                          const unsigned short* BT, int ldb,
                          const unsigned short* A2, int lda2,
                          const unsigned short* B2, int ldb2, int K1,
                          const float* bias, void* Cout, int ldc, int K,
                          const float* cin, int OUT, long obase, long tm, long tn,
                          unsigned short* As, unsigned short* Bs,
                          float* g1_qf, unsigned short* g1_qb,
                          unsigned short* g1_kxb, unsigned short* g1_vxT) {
    constexpr int TR = WAVES_M * WM * 16;
    constexpr int TC = (4 / WAVES_M) * WN * 16;
    constexpr int NL = TR / 32 + TC / 32;   // global_load_lds per wave per stage
    const int tid = threadIdx.x;
    const int w = tid >> 6, lane = tid & 63;
    const int lm = lane & 15, quad = lane >> 4;
    const int m_off = (w % WAVES_M) * WM * 16;
    const int n_off = (w / WAVES_M) * WN * 16;
    const int lrow8 = lane >> 3;
    const int lcol_sw = (((lane & 7) ^ lrow8) * 8);

    f32x4 acc[WM][WN];
    #pragma unroll
    for (int mi = 0; mi < WM; ++mi)
        #pragma unroll
        for (int ni = 0; ni < WN; ++ni) acc[mi][ni] = f32x4{0.f, 0.f, 0.f, 0.f};

    auto stage = [&](int k0, int pb) {
        const unsigned short* Ab; const unsigned short* Bb;
        int la, lb, kc;
        if (k0 < K1) { Ab = A;  Bb = BT; la = lda;  lb = ldb;  kc = k0; }
        else         { Ab = A2; Bb = B2; la = lda2; lb = ldb2; kc = k0 - K1; }
        unsigned short* Asb = As + pb * (TR * 64);
        unsigned short* Bsb = Bs + pb * (TC * 64);
        #pragma unroll
        for (int i = 0; i < TR / 32; ++i) {
            int rr = w * (TR / 4) + i * 8;
            const unsigned short* ga = Ab + (tm + rr + lrow8) * la + kc + lcol_sw;
            __builtin_amdgcn_global_load_lds((gas_ptr)ga, (las_ptr)(Asb + rr * 64), 16, 0, 0);
        }
        #pragma unroll
        for (int i = 0; i < TC / 32; ++i) {
            int rr = w * (TC / 4) + i * 8;
            const unsigned short* gb = Bb + (tn + rr + lrow8) * lb + kc + lcol_sw;
            __builtin_amdgcn_global_load_lds((gas_ptr)gb, (las_ptr)(Bsb + rr * 64), 16, 0, 0);
        }
    };

    stage(0, 0);
    const int nt = K >> 6;
    for (int t = 0; t < nt; ++t) {
        const int cur = t & 1;
        if (t + 1 < nt) {
            stage((t + 1) << 6, cur ^ 1);
            waitcnt_vm<NL>();     // wait only for buf[cur]'s loads; next NL stay in flight
        } else {
            waitcnt_vm<0>();
        }
        hard_barrier();
        const unsigned short* Asb = As + cur * (TR * 64);
        const unsigned short* Bsb = Bs + cur * (TC * 64);
        #pragma unroll
        for (int kk = 0; kk < 2; ++kk) {
            bf16x8 af[WM], bfr[WN];
            #pragma unroll
            for (int mi = 0; mi < WM; ++mi) {
                int r = m_off + mi * 16 + lm;
                af[mi] = *(const bf16x8*)(Asb + r * 64 + (((kk * 4 + quad) ^ (r & 7)) * 8));
            }
            #pragma unroll
            for (int ni = 0; ni < WN; ++ni) {
                int r = n_off + ni * 16 + lm;
                bfr[ni] = *(const bf16x8*)(Bsb + r * 64 + (((kk * 4 + quad) ^ (r & 7)) * 8));
            }
            #pragma unroll
            for (int mi = 0; mi < WM; ++mi)
                #pragma unroll
                for (int ni = 0; ni < WN; ++ni)
                    acc[mi][ni] = __builtin_amdgcn_mfma_f32_16x16x32_bf16(
                        af[mi], bfr[ni], acc[mi][ni], 0, 0, 0);
        }
        hard_barrier();   // all waves done reading buf[cur]; safe to restage it
    }

    #pragma unroll
    for (int mi = 0; mi < WM; ++mi) {
        #pragma unroll
        for (int ni = 0; ni < WN; ++ni) {
            long col = tn + n_off + ni * 16 + lm;
            float bv = bias[col];
            #pragma unroll
            for (int r = 0; r < 4; ++r) {
                long row = tm + m_off + mi * 16 + quad * 4 + r;   // C/D: col=lane&15, row=quad*4+reg
                float v = acc[mi][ni][r] + bv;
                if (G1E) {
                    if (col < 768) {
                        g1_qf[row * 768 + col] = v;
                        g1_qb[row * 768 + col] = f2bf(v);
                    } else if (col < 1536) {
                        g1_kxb[row * 768 + (col - 768)] = f2bf(v);
                    } else {
                        int j = (int)col - 1536, h = j >> 6, d = j & 63;
                        int bb = (int)row >> 8, nn = (int)row & 255;
                        g1_vxT[((long)(bb * 12 + h) * 64 + d) * 256 + nn] = f2bf(v);
                    }
                } else {
                    long idx = obase + row * ldc + col;
                    if (cin) v += cin[idx];
                    if (OUT == 0) ((float*)Cout)[idx] = v;
                    else ((unsigned short*)Cout)[idx] = f2bf(v);
                }
            }
        }
    }
}

// standard wrapper: batch z -> zb=z/12, zh=z%12
template <int WM, int WN, int WAVES_M, bool G1E>
__global__ __launch_bounds__(256)
void gemm_bf16_kernel(const unsigned short* __restrict__ A, int lda,
                      const unsigned short* __restrict__ BT, int ldb,
                      const float* __restrict__ bias,
                      void* __restrict__ Cout, int ldc, int K,
                      const float* __restrict__ cin, int OUT,
                      long aZb, long aZh, long bZb, long bZh, long oZb, long oZh,
                      float* __restrict__ g1_qf, unsigned short* __restrict__ g1_qb,
                      unsigned short* __restrict__ g1_kxb,
                      unsigned short* __restrict__ g1_vxT) {
    constexpr int TR = WAVES_M * WM * 16;
    constexpr int TC = (4 / WAVES_M) * WN * 16;
    __shared__ unsigned short As[2 * TR * 64];
    __shared__ unsigned short Bs[2 * TC * 64];
    const int z = blockIdx.z, zb = z / 12, zh = z % 12;
    gemm_body<WM, WN, WAVES_M, G1E>(
        A + zb * aZb + zh * aZh, lda, BT + zb * bZb + zh * bZh, ldb,
        nullptr, 0, nullptr, 0, 1 << 30,
        bias, Cout, ldc, K, cin, OUT, zb * oZb + zh * oZh,
        (long)blockIdx.y * TR, (long)blockIdx.x * TC, As, Bs,
        g1_qf, g1_qb, g1_kxb, g1_vxT);
}

// fused qW + SG launch (both depend only on GEMM1): 1D grid of 1152 + 384
__global__ __launch_bounds__(256)
void gemm_qwsg_kernel(const unsigned short* __restrict__ qb,
                      const unsigned short* __restrict__ wkvb,
                      const unsigned short* __restrict__ kxb,
                      const float* __restrict__ zbuf,
                      unsigned short* __restrict__ qWb,
                      float* __restrict__ sgbuf) {
    __shared__ unsigned short As[2 * 64 * 64];
    __shared__ unsigned short Bs[2 * 64 * 64];
    int bid = blockIdx.x;
    if (bid < 1152) {
        // qW: qW_h = q_h @ Wk_h^T  (512x768, K=64), bf16 out
        int bx = bid % 12, by = (bid / 12) % 8, h = bid / 96;
        gemm_body<2, 2, 2, false>(
            qb + h * 64, 768, wkvb + h * 64, 1536,
            nullptr, 0, nullptr, 0, 1 << 30,
            zbuf, qWb, 768, 64, nullptr, 1, (long)h * 393216,
            (long)by * 64, (long)bx * 64, As, Bs,
            nullptr, nullptr, nullptr, nullptr);
    } else {
        // SG: sg = q_h @ k_x,h^T per (b,h)  (256x256, K=64), fp32 out
        int bid2 = bid - 1152;
        int bx = bid2 % 4, by = (bid2 / 4) % 4, z = bid2 / 16;
        int zb = z / 12, zh = z % 12;
        gemm_body<2, 2, 2, false>(
            qb + zb * 196608 + zh * 64, 768, kxb + zb * 196608 + zh * 64, 768,
            nullptr, 0, nullptr, 0, 1 << 30,
            zbuf, sgbuf, 256, 64, nullptr, 0,
            (long)zb * 786432 + (long)zh * 65536,
            (long)by * 64, (long)bx * 64, As, Bs,
            nullptr, nullptr, nullptr, nullptr);
    }
}

// concat-K wrapper: attnb = bf16([simbar | ag] @ [WvT | vxT]^T + outg0)
template <int WM, int WN, int WAVES_M>
__global__ __launch_bounds__(256)
void gemm_concat_kernel(const unsigned short* __restrict__ A, int lda, long aZb, long aZh,
                        const unsigned short* __restrict__ BT, int ldb, long bZb, long bZh,
                        const unsigned short* __restrict__ A2, int lda2, long a2Zb, long a2Zh,
                        const unsigned short* __restrict__ B2, int ldb2, long b2Zb, long b2Zh,
                        int K1, int K, const float* __restrict__ bias,
                        void* __restrict__ Cout, int ldc,
                        const float* __restrict__ cin, int OUT, long oZb, long oZh) {
    constexpr int TR = WAVES_M * WM * 16;
    constexpr int TC = (4 / WAVES_M) * WN * 16;
    __shared__ unsigned short As[2 * TR * 64];
    __shared__ unsigned short Bs[2 * TC * 64];
    const int z = blockIdx.z, zb = z / 12, zh = z % 12;
    gemm_body<WM, WN, WAVES_M, false>(
        A + zb * aZb + zh * aZh, lda, BT + zb * bZb + zh * bZh, ldb,
        A2 + zb * a2Zb + zh * a2Zh, lda2, B2 + zb * b2Zb + zh * b2Zh, ldb2, K1,
        bias, Cout, ldc, K, cin, OUT, zb * oZb + zh * oZh,
        (long)blockIdx.y * TR, (long)blockIdx.x * TC, As, Bs,
        nullptr, nullptr, nullptr, nullptr);
}

// ---------------- fused attention: sl MFMA + softmax + simbar ----------------
// Block per n_ = b*256+n, 512 threads (8 waves, 2 groups of 4).
// Pass 1: group g handles k-chunks [6g, 6g+6); each group register-prefetches the
//   next 64-wide sim chunk, double-buffered LDS per group, lgkm-only barrier so
//   prefetch loads stay in flight. Partial accs combined via scl[2][..].
// Softmax (waves 0-5, 2 heads each) over [sg(256)|sl(64)]; ag -> agb bf16;
//   al kept in LDS; alm*bkv_v -> outg0.
// Pass 2: simbar[h][n_][c] = sum_m al[h][m]*sim[n_][m][c]; sim slice is L2-hot.
__global__ __launch_bounds__(512, 4)
void attn_fused_kernel(const float* __restrict__ sim,
                       const unsigned short* __restrict__ qWb,
                       const float* __restrict__ qf,
                       const float* __restrict__ bkv,
                       const float* __restrict__ sgbuf,
                       unsigned short* __restrict__ agb,
                       float* __restrict__ outg0,
                       unsigned short* __restrict__ simbar) {
    __shared__ unsigned short qw_s[12 * 784];     // 18816 B
    __shared__ unsigned short sim_s[2][2][64 * 64];   // [group][dbuf], 32768 B
    __shared__ float q_l[768];
    __shared__ float slb_s[12];
    __shared__ float scl[2][12][68];              // per-group partial sl
    __shared__ float al_s[12][64];

    const int t = threadIdx.x;
    const int lane = t & 63, w = t >> 6;
    const int lm = lane & 15, quad = lane >> 4;
    const int g = w >> 2, wl = w & 3;
    const int tg = t & 255;
    const int n = blockIdx.x, b = blockIdx.y;
    const int n_ = b * 256 + n;
    const float* simn = sim + (long)n_ * 49152;   // 64 x 768

    // stage qW (12 rows x 768): h = t>>5, 3 chunks of 8 bf16 each
    {
        const int h = t >> 5, c0 = t & 31;
        if (h < 12) {
            const unsigned short* src = qWb + ((long)h * 512 + n_) * 768;
            #pragma unroll
            for (int j = 0; j < 3; ++j) {
                int ch = c0 + 32 * j;
                *(bf16x8*)(qw_s + h * 784 + ch * 8) = *(const bf16x8*)(src + ch * 8);
            }
        }
    }
    q_l[t] = qf[(long)n_ * 768 + t];
    if (t < 256) q_l[t + 512] = qf[(long)n_ * 768 + t + 512];

    // prefetch group's chunk 0: thread covers rows r0 and r0+32
    const int r0 = tg >> 3, q8 = tg & 7, r1 = r0 + 32;
    const int kb = g * 6;   // first chunk index for this group
    float4 p0a, p0b, p1a, p1b;
    {
        const float* g0 = simn + r0 * 768 + kb * 64 + q8 * 8;
        p0a = *(const float4*)g0; p0b = *(const float4*)(g0 + 4);
        const float* g1 = simn + r1 * 768 + kb * 64 + q8 * 8;
        p1a = *(const float4*)g1; p1b = *(const float4*)(g1 + 4);
    }
    __syncthreads();   // qw_s, q_l staged
    if (t < 12) {      // sl bias term: q[h] . bkv_k[h]
        float s = 0.f;
        #pragma unroll 8
        for (int d = 0; d < 64; ++d) s += q_l[t * 64 + d] * bkv[t * 64 + d];
        slb_s[t] = s;
    }

    // Pass 1: each group does 6 chunks, double-buffered + reg prefetch
    f32x4 acc = {};
    #pragma unroll
    for (int cc = 0; cc < 6; ++cc) {
        const int k0 = (kb + cc) * 64;
        unsigned short* buf = sim_s[g][cc & 1];
        union { bf16x8 v; unsigned short u[8]; } pk;
        pk.u[0] = f2bf(p0a.x); pk.u[1] = f2bf(p0a.y);
        pk.u[2] = f2bf(p0a.z); pk.u[3] = f2bf(p0a.w);
        pk.u[4] = f2bf(p0b.x); pk.u[5] = f2bf(p0b.y);
        pk.u[6] = f2bf(p0b.z); pk.u[7] = f2bf(p0b.w);
        *(bf16x8*)(buf + r0 * 64 + ((q8 ^ (r0 & 7)) * 8)) = pk.v;
        pk.u[0] = f2bf(p1a.x); pk.u[1] = f2bf(p1a.y);
        pk.u[2] = f2bf(p1a.z); pk.u[3] = f2bf(p1a.w);
        pk.u[4] = f2bf(p1b.x); pk.u[5] = f2bf(p1b.y);
        pk.u[6] = f2bf(p1b.z); pk.u[7] = f2bf(p1b.w);
        *(bf16x8*)(buf + r1 * 64 + ((q8 ^ (r1 & 7)) * 8)) = pk.v;
        if (cc < 5) {   // prefetch next chunk; stays in flight across lds_barrier
            const float* g0 = simn + r0 * 768 + k0 + 64 + q8 * 8;
            p0a = *(const float4*)g0; p0b = *(const float4*)(g0 + 4);
            const float* g1 = simn + r1 * 768 + k0 + 64 + q8 * 8;
            p1a = *(const float4*)g1; p1b = *(const float4*)(g1 + 4);
        }
        lds_barrier();
        #pragma unroll
        for (int kk = 0; kk < 2; ++kk) {
            int r = wl * 16 + lm;
            bf16x8 af = *(const bf16x8*)(buf + r * 64 + (((kk * 4 + quad) ^ (r & 7)) * 8));
            // lm in 12..15 reads junk LDS (in-bounds of block); those lanes' cols unused
            bf16x8 bfr = *(const bf16x8*)(qw_s + lm * 784 + k0 + kk * 32 + quad * 8);
            acc = __builtin_amdgcn_mfma_f32_16x16x32_bf16(af, bfr, acc, 0, 0, 0);
        }
    }
    if (lm < 12) {
        #pragma unroll
        for (int r = 0; r < 4; ++r)
            scl[g][lm][wl * 16 + quad * 4 + r] = acc[r];
    }
    __syncthreads();

    // softmax: waves 0..5, heads h = 2w, 2w+1
    if (w < 6) {
        #pragma unroll
        for (int i = 0; i < 2; ++i) {
            const int h = w * 2 + i;
            const float* sgr = sgbuf + (long)(b * 12 + h) * 65536 + (long)n * 256;
            float v0 = sgr[lane] * 0.125f, v1 = sgr[lane + 64] * 0.125f,
                  v2 = sgr[lane + 128] * 0.125f, v3 = sgr[lane + 192] * 0.125f;
            float v4 = (scl[0][h][lane] + scl[1][h][lane] + slb_s[h]) * 0.125f;
            float mx = fmaxf(fmaxf(fmaxf(v0, v1), fmaxf(v2, v3)), v4);
            #pragma unroll
            for (int off = 32; off > 0; off >>= 1) mx = fmaxf(mx, __shfl_xor(mx, off));
            float e0 = __expf(v0 - mx), e1 = __expf(v1 - mx), e2 = __expf(v2 - mx),
                  e3 = __expf(v3 - mx), e4 = __expf(v4 - mx);
            float s = e0 + e1 + e2 + e3 + e4;
            #pragma unroll
            for (int off = 32; off > 0; off >>= 1) s += __shfl_xor(s, off);
            float inv = __frcp_rn(s);
            unsigned short* agr = agb + (long)(b * 12 + h) * 65536 + (long)n * 256;
            agr[lane] = f2bf(e0 * inv); agr[lane + 64] = f2bf(e1 * inv);
            agr[lane + 128] = f2bf(e2 * inv); agr[lane + 192] = f2bf(e3 * inv);
            float al = e4 * inv;
            al_s[h][lane] = al;
            float am = al;
            #pragma unroll
            for (int off = 32; off > 0; off >>= 1) am += __shfl_xor(am, off);
            outg0[(long)n_ * 768 + h * 64 + lane] = am * bkv[768 + h * 64 + lane];
        }
    }
    __syncthreads();

    // Pass 2: simbar; sim slice L2-hot from pass 1. Col t (all), col t+512 (waves 0-3).
    {
        float a[12];
        #pragma unroll
        for (int h = 0; h < 12; ++h) a[h] = 0.f;
        #pragma unroll 4
        for (int m = 0; m < 64; ++m) {
            float s = simn[(long)m * 768 + t];
            #pragma unroll
            for (int h = 0; h < 12; ++h) a[h] += al_s[h][m] * s;
        }
        #pragma unroll
        for (int h = 0; h < 12; ++h)
            simbar[((long)h * 512 + n_) * 768 + t] = f2bf(a[h]);
    }
    if (w < 4) {   // wave-uniform branch
        float a[12];
        #pragma unroll
        for (int h = 0; h < 12; ++h) a[h] = 0.f;
        #pragma unroll 4
        for (int m = 0; m < 64; ++m) {
            float s = simn[(long)m * 768 + 512 + t];
            #pragma unroll
            for (int h = 0; h < 12; ++h) a[h] += al_s[h][m] * s;
        }
        #pragma unroll
        for (int h = 0; h < 12; ++h)
            simbar[((long)h * 512 + n_) * 768 + 512 + t] = f2bf(a[h]);
    }
}

// ---------------- launch ----------------

extern "C" void kernel_launch(void* const* d_in, const int* in_sizes, int n_in,
                              void* d_out, int out_size, void* d_ws, size_t ws_size,
                              hipStream_t stream) {
    const float* x   = (const float*)d_in[0];   // (2,256,768)
    const float* sim = (const float*)d_in[1];   // (2,256,64,768)
    const float* Wq  = (const float*)d_in[2];   // (768,768)
    const float* bq  = (const float*)d_in[3];   // (768)
    const float* Wkv = (const float*)d_in[4];   // (768,1536)
    const float* bkv = (const float*)d_in[5];   // (1536)
    const float* Wp  = (const float*)d_in[6];   // (768,768)
    const float* bp  = (const float*)d_in[7];   // (768)
    float* out = (float*)d_out;                 // (2,256,768) fp32

    char* ws = (char*)d_ws;
    size_t off = 0;
    auto alloc = [&](size_t bytes) {
        char* p = ws + off;
        off += (bytes + 255) & ~(size_t)255;
        return p;
    };
    unsigned short* xb     = (unsigned short*)alloc(512UL * 768 * 2);       // x bf16
    unsigned short* w1t    = (unsigned short*)alloc(2304UL * 768 * 2);      // [Wq|Wkv]^T bf16
    unsigned short* wkvb   = (unsigned short*)alloc(768UL * 1536 * 2);      // Wkv bf16
    unsigned short* wpt    = (unsigned short*)alloc(768UL * 768 * 2);       // Wp^T bf16
    float*          qf     = (float*)alloc(512UL * 768 * 4);                // q fp32
    unsigned short* qb     = (unsigned short*)alloc(512UL * 768 * 2);       // q bf16
    unsigned short* kxb    = (unsigned short*)alloc(512UL * 768 * 2);       // k_x bf16
    unsigned short* vxT    = (unsigned short*)alloc(24UL * 64 * 256 * 2);   // v_x^T per (b,h)
    unsigned short* qWb    = (unsigned short*)alloc(12UL * 512 * 768 * 2);  // qW bf16
    float*          sgbuf  = (float*)alloc(24UL * 65536 * 4);               // sg fp32
    unsigned short* agb    = (unsigned short*)alloc(24UL * 65536 * 2);      // ag bf16
    float*          outg0  = (float*)alloc(512UL * 768 * 4);                // alm*bkv_v fp32
    unsigned short* simbar = (unsigned short*)alloc(12UL * 512 * 768 * 2);  // simbar bf16
    unsigned short* attnb  = (unsigned short*)alloc(512UL * 768 * 2);       // attn out bf16
    float*          bias1  = (float*)alloc(2304UL * 4);                     // [bq|bkv]
    float*          zbuf   = (float*)alloc(768UL * 4);                      // zeros

    // prep (2 launches)
    prep_cast_kernel<<<1548, 256, 0, stream>>>(x, xb, Wkv, wkvb, bq, bkv, bias1, zbuf);
    transpose3_kernel<<<dim3(48, 12), dim3(64, 16), 0, stream>>>(Wq, Wkv, Wp, w1t, wpt);

    // GEMM1: x @ [Wq|Wkv] + bias -> qf/qb, kxb, vxT   (512 x 2304, K=768), 32x64 tiles
    gemm_bf16_kernel<1, 2, 2, true><<<dim3(36, 16, 1), 256, 0, stream>>>(
        xb, 768, w1t, 768, bias1, nullptr, 768, 768, nullptr, 0,
        0, 0, 0, 0, 0, 0, qf, qb, kxb, vxT);

    // qW (512x768 K=64 per head) + SG (256x256 K=64 per (b,h)) fused: 1536 blocks
    gemm_qwsg_kernel<<<1536, 256, 0, stream>>>(qb, wkvb, kxb, zbuf, qWb, sgbuf);

    // fused attention: split-K pipelined sl MFMA + softmax + simbar
    attn_fused_kernel<<<dim3(256, 2), 512, 0, stream>>>(
        sim, qWb, qf, bkv, sgbuf, agb, outg0, simbar);

    // attnb = bf16([simbar | ag] @ [WvT | vxT]^T + outg0), per (b,h), K=768+256
    gemm_concat_kernel<1, 1, 2><<<dim3(2, 8, 24), 256, 0, stream>>>(
        simbar, 768, 196608, 393216,
        w1t + 1536L * 768, 768, 0, 49152,
        agb, 256, 786432, 65536,
        vxT, 256, 196608, 16384,
        768, 1024, zbuf, attnb, 768, outg0, 1, 196608, 64);

    // GEMM3: out = attnb @ Wp + bp   (512x768, K=768), 32x32 tiles -> 384 blocks
    gemm_bf16_kernel<1, 1, 2, false><<<dim3(24, 16, 1), 256, 0, stream>>>(
        attnb, 768, wpt, 768, bp, out, 768, 768, nullptr, 0,
        0, 0, 0, 0, 0, 0, nullptr, nullptr, nullptr, nullptr);
}